// Round 10
// baseline (294.657 us; speedup 1.0000x reference)
//
#include <hip/hip_runtime.h>
#include <math.h>

// Outputs are a pure function of obs's class (NC=1000); heads (am/sd/cr)
// are a pure function of the VQ CODE (VQN=512).
//
// R13: falsified so far: VMEM scheduling (R9/R10), occupancy cap (R11),
// weight-traffic amortization (R6/R12). Untested lever: the cross-thread
// K-chain split itself (2 barriers/layer, 256-thread lockstep, 1.5-2.5
// dispatch rounds). New trunk: one 32-lane group owns one class
// end-to-end; thread q computes outputs 4q..4q+3 completely with R3's
// 4-chain per-output structure (f4 loads), 1 barrier/layer, wave-local
// VQ reduce (shfl width-32, min-lex as R9). 8 classes/block -> 125 trunk
// + 256 head blocks = 381 -> ONE dispatch round. Heads verbatim R9.
// Trunk/zp chains bit-identical to R3/R7 lineage; VQ chains verbatim R9
// => absmax 0.

typedef float f4 __attribute__((ext_vector_type(4)));
typedef float f2 __attribute__((ext_vector_type(2)));

__device__ __forceinline__ float sigmoidf_(float x){ return 1.0f/(1.0f + expf(-x)); }

__global__ __launch_bounds__(256) void compute_kernel(
    const float* __restrict__ embed,
    const float* __restrict__ W1, const float* __restrict__ b1,
    const float* __restrict__ W2, const float* __restrict__ b2,
    const float* __restrict__ W3, const float* __restrict__ b3,
    const float* __restrict__ Wp, const float* __restrict__ bp,
    const float* __restrict__ cb,
    const float* __restrict__ Wa, const float* __restrict__ ba,
    const float* __restrict__ Ws, const float* __restrict__ bs,
    const float* __restrict__ Wc1, const float* __restrict__ bc1,
    const float* __restrict__ Wc2, const float* __restrict__ bc2,
    const float* __restrict__ Wc3, const float* __restrict__ bc3,
    const float* __restrict__ Wc4, const float* __restrict__ bc4,
    float* __restrict__ am_c, float* __restrict__ sd_c,
    float* __restrict__ cr_c, int* __restrict__ idx_t, float* __restrict__ e_t,
    float* __restrict__ loss_slot, int VQN, int NC, int nTB)
{
    const int bid = blockIdx.x;
    const int t   = threadIdx.x;     // 0..255
    if (bid == 0 && t == 0) *loss_slot = 0.0f;   // d_out is poisoned each call

    // trunk LDS: 8 classes, group-private regions
    __shared__ double X[8][128], Y[8][128];
    __shared__ double zp8[8][64];
    __shared__ float  qv8[8][64];
    // head LDS (verbatim R9)
    __shared__ float  qvh[2][64];
    __shared__ float  fpart[2][4][128];
    __shared__ float  gpart[2][2][128];
    __shared__ float  h1s[2][128], h2s[2][128], h3s[2][32];

    if (bid < nTB) {
        // ====== trunk + VQ: group g (32 lanes) owns class c end-to-end ======
        const int g  = t >> 5;           // 0..7
        const int q  = t & 31;
        int c = bid * 8 + g;
        if (c >= NC) c = NC - 1;         // clamp (idempotent dup write)
        const int o4 = q << 2;           // this thread's 4 outputs

        // y = embed[c]: one f4 per lane
        {
            f4 e = *(const f4*)(embed + (size_t)c * 128 + o4);
            X[g][o4+0] = (double)e.x; X[g][o4+1] = (double)e.y;
            X[g][o4+2] = (double)e.z; X[g][o4+3] = (double)e.w;
        }
        __syncthreads();

        // Layer: thread q computes outputs o4..o4+3 fully. Per output:
        // R3's 4 chains (i ≡ h mod 4), chain 0 carries bias, combine
        // (a0+a1)+(a2+a3) then ReLU — bit-identical per-output math.
#define LAYER(Wm, bv, IN, OUT)                                                \
        {                                                                     \
            f4 bb = *(const f4*)(bv + o4);                                    \
            double a0[4] = {(double)bb.x,(double)bb.y,(double)bb.z,(double)bb.w};\
            double a1[4] = {0.0,0.0,0.0,0.0};                                 \
            double a2[4] = {0.0,0.0,0.0,0.0};                                 \
            double a3[4] = {0.0,0.0,0.0,0.0};                                 \
            _Pragma("unroll 8")                                               \
            for (int s = 0; s < 32; ++s) {                                    \
                int i = s << 2;                                               \
                f4 w0 = *(const f4*)(Wm + (size_t)(i+0) * 128 + o4);          \
                f4 w1 = *(const f4*)(Wm + (size_t)(i+1) * 128 + o4);          \
                f4 w2 = *(const f4*)(Wm + (size_t)(i+2) * 128 + o4);          \
                f4 w3 = *(const f4*)(Wm + (size_t)(i+3) * 128 + o4);          \
                double x0 = IN[g][i+0], x1 = IN[g][i+1];                      \
                double x2 = IN[g][i+2], x3 = IN[g][i+3];                      \
                a0[0]=fma(x0,(double)w0.x,a0[0]); a0[1]=fma(x0,(double)w0.y,a0[1]);\
                a0[2]=fma(x0,(double)w0.z,a0[2]); a0[3]=fma(x0,(double)w0.w,a0[3]);\
                a1[0]=fma(x1,(double)w1.x,a1[0]); a1[1]=fma(x1,(double)w1.y,a1[1]);\
                a1[2]=fma(x1,(double)w1.z,a1[2]); a1[3]=fma(x1,(double)w1.w,a1[3]);\
                a2[0]=fma(x2,(double)w2.x,a2[0]); a2[1]=fma(x2,(double)w2.y,a2[1]);\
                a2[2]=fma(x2,(double)w2.z,a2[2]); a2[3]=fma(x2,(double)w2.w,a2[3]);\
                a3[0]=fma(x3,(double)w3.x,a3[0]); a3[1]=fma(x3,(double)w3.y,a3[1]);\
                a3[2]=fma(x3,(double)w3.z,a3[2]); a3[3]=fma(x3,(double)w3.w,a3[3]);\
            }                                                                 \
            _Pragma("unroll")                                                 \
            for (int o = 0; o < 4; ++o) {                                     \
                double acc = (a0[o] + a1[o]) + (a2[o] + a3[o]);               \
                OUT[g][o4 + o] = acc > 0.0 ? acc : 0.0;                       \
            }                                                                 \
        }                                                                     \
        __syncthreads();

        LAYER(W1, b1, X, Y)
        LAYER(W2, b2, Y, X)
        LAYER(W3, b3, X, Y)
#undef LAYER

        // zp = z3 @ Wp + bp (64 outputs): lanes q<16, outputs 4q..4q+3,
        // R3/R7 4-chain structure (i ≡ h mod 4), no ReLU.
        if (q < 16) {
            const int o4p = q << 2;
            f4 bb = *(const f4*)(bp + o4p);
            double a0[4] = {(double)bb.x,(double)bb.y,(double)bb.z,(double)bb.w};
            double a1[4] = {0.0,0.0,0.0,0.0};
            double a2[4] = {0.0,0.0,0.0,0.0};
            double a3[4] = {0.0,0.0,0.0,0.0};
            #pragma unroll 8
            for (int s = 0; s < 32; ++s) {
                int i = s << 2;
                f4 w0 = *(const f4*)(Wp + (size_t)(i+0) * 64 + o4p);
                f4 w1 = *(const f4*)(Wp + (size_t)(i+1) * 64 + o4p);
                f4 w2 = *(const f4*)(Wp + (size_t)(i+2) * 64 + o4p);
                f4 w3 = *(const f4*)(Wp + (size_t)(i+3) * 64 + o4p);
                double x0 = Y[g][i+0], x1 = Y[g][i+1];
                double x2 = Y[g][i+2], x3 = Y[g][i+3];
                a0[0]=fma(x0,(double)w0.x,a0[0]); a0[1]=fma(x0,(double)w0.y,a0[1]);
                a0[2]=fma(x0,(double)w0.z,a0[2]); a0[3]=fma(x0,(double)w0.w,a0[3]);
                a1[0]=fma(x1,(double)w1.x,a1[0]); a1[1]=fma(x1,(double)w1.y,a1[1]);
                a1[2]=fma(x1,(double)w1.z,a1[2]); a1[3]=fma(x1,(double)w1.w,a1[3]);
                a2[0]=fma(x2,(double)w2.x,a2[0]); a2[1]=fma(x2,(double)w2.y,a2[1]);
                a2[2]=fma(x2,(double)w2.z,a2[2]); a2[3]=fma(x2,(double)w2.w,a2[3]);
                a3[0]=fma(x3,(double)w3.x,a3[0]); a3[1]=fma(x3,(double)w3.y,a3[1]);
                a3[2]=fma(x3,(double)w3.z,a3[2]); a3[3]=fma(x3,(double)w3.w,a3[3]);
            }
            #pragma unroll
            for (int o = 0; o < 4; ++o)
                zp8[g][o4p + o] = (a0[o] + a1[o]) + (a2[o] + a3[o]);
        }
        __syncthreads();

        // VQ argmin: lane q owns codes q, q+32, ... (ascending, strict-<
        // first-min); distance chains verbatim R9 (s0/s1 order).
        double best = 1e300; int bi = 0;
        for (int k = q; k < VQN; k += 32) {
            const float* crow = cb + (size_t)k * 64;
            double s0 = 0.0, s1 = 0.0;
            #pragma unroll
            for (int j4 = 0; j4 < 16; ++j4) {
                f4 v = *(const f4*)(crow + (j4 << 2));
                int j = j4 << 2;
                double d0 = zp8[g][j+0] - (double)v.x;
                double d1 = zp8[g][j+1] - (double)v.y;
                double d2 = zp8[g][j+2] - (double)v.z;
                double d3 = zp8[g][j+3] - (double)v.w;
                s0 = fma(d0, d0, s0);  s1 = fma(d1, d1, s1);
                s0 = fma(d2, d2, s0);  s1 = fma(d3, d3, s1);
            }
            double s = s0 + s1;
            if (s < best) { best = s; bi = k; }
        }
        // (min d, min idx) lattice within the 32-lane group
        for (int off = 16; off > 0; off >>= 1) {
            double od = __shfl_down(best, off, 32);
            int    oi = __shfl_down(bi, off, 32);
            if (od < best || (od == best && oi < bi)) { best = od; bi = oi; }
        }
        const int widx = __shfl(bi, 0, 32);

        if (q < 16) {
            f4 cq = *(const f4*)(cb + (size_t)widx * 64 + (q << 2));
            qv8[g][(q<<2)+0] = cq.x; qv8[g][(q<<2)+1] = cq.y;
            qv8[g][(q<<2)+2] = cq.z; qv8[g][(q<<2)+3] = cq.w;
        }
        __syncthreads();

        if (q == 0) {
            idx_t[c] = widx;
            double e0 = 0.0, e1 = 0.0;
            for (int j = 0; j < 64; j += 2) {
                double d0 = (double)qv8[g][j]   - zp8[g][j];
                double d1 = (double)qv8[g][j+1] - zp8[g][j+1];
                e0 = fma(d0, d0, e0); e1 = fma(d1, d1, e1);
            }
            e_t[c] = (float)(e0 + e1);   // sum over 64 dims of (quant-z)^2
        }
    } else {
        // ============ heads per CODE (2 codes/block, verbatim R9) ============
        const int g  = t >> 7;                 // code slot 0/1
        const int tt = t & 127;
        int k = (bid - nTB) * 2 + g;
        const int kk = (k < VQN) ? k : VQN - 1;    // clamp (dup-safe)
        const int q4 = (tt & 31) << 2;

        if (tt < 64) qvh[g][tt] = cb[(size_t)kk * 64 + tt];
        __syncthreads();

        // H1: slots (tt>>5): 0=Wa-even, 1=Wa-odd, 2=Ws-even, 3=Ws-odd.
        {
            const int m  = tt >> 6;
            const int hh = (tt >> 5) & 1;
            const float* Wm = m ? Ws : Wa;
            const float* bm = m ? bs : ba;
            float a0 = hh ? 0.0f : bm[q4+0];
            float a1 = hh ? 0.0f : bm[q4+1];
            float a2 = hh ? 0.0f : bm[q4+2];
            float a3 = hh ? 0.0f : bm[q4+3];
            #pragma unroll
            for (int s = 0; s < 32; ++s) {
                f4 w = *(const f4*)(Wm + (size_t)(hh + (s << 1)) * 128 + q4);
                float qj = qvh[g][hh + (s << 1)];
                a0 = fmaf(qj, w.x, a0);
                a1 = fmaf(qj, w.y, a1);
                a2 = fmaf(qj, w.z, a2);
                a3 = fmaf(qj, w.w, a3);
            }
            fpart[g][tt >> 5][q4+0] = a0; fpart[g][tt >> 5][q4+1] = a1;
            fpart[g][tt >> 5][q4+2] = a2; fpart[g][tt >> 5][q4+3] = a3;
        }
        __syncthreads();

        // H2: tt<64 compute Wc1 chains; tt>=64 combine+store am/sd per code
        if (tt < 64) {
            const int hh = tt >> 5;
            float a0 = hh ? 0.0f : bc1[q4+0];
            float a1 = hh ? 0.0f : bc1[q4+1];
            float a2 = hh ? 0.0f : bc1[q4+2];
            float a3 = hh ? 0.0f : bc1[q4+3];
            #pragma unroll
            for (int s = 0; s < 32; ++s) {
                f4 w = *(const f4*)(Wc1 + (size_t)(hh + (s << 1)) * 128 + q4);
                float qj = qvh[g][hh + (s << 1)];
                a0 = fmaf(qj, w.x, a0);
                a1 = fmaf(qj, w.y, a1);
                a2 = fmaf(qj, w.z, a2);
                a3 = fmaf(qj, w.w, a3);
            }
            gpart[g][hh][q4+0] = a0; gpart[g][hh][q4+1] = a1;
            gpart[g][hh][q4+2] = a2; gpart[g][hh][q4+3] = a3;
        } else {
            int o = (tt - 64) << 1;
            am_c[(size_t)kk * 128 + o]     = sigmoidf_(fpart[g][0][o]   + fpart[g][1][o]);
            am_c[(size_t)kk * 128 + o + 1] = sigmoidf_(fpart[g][0][o+1] + fpart[g][1][o+1]);
            sd_c[(size_t)kk * 128 + o]     = sigmoidf_(fpart[g][2][o]   + fpart[g][3][o])   * 1.0f + 1e-8f;
            sd_c[(size_t)kk * 128 + o + 1] = sigmoidf_(fpart[g][2][o+1] + fpart[g][3][o+1]) * 1.0f + 1e-8f;
        }
        __syncthreads();
        h1s[g][tt] = sigmoidf_(gpart[g][0][tt] + gpart[g][1][tt]);
        __syncthreads();

        // critic layer 2 (128->128): s=0..63 sequential
        {
            const int o2 = (tt & 63) << 1;
            const int hh = tt >> 6;
            float a0 = hh ? 0.0f : bc2[o2+0];
            float a1 = hh ? 0.0f : bc2[o2+1];
            #pragma unroll
            for (int s = 0; s < 64; ++s) {
                f2 w = *(const f2*)(Wc2 + (size_t)(hh + (s << 1)) * 128 + o2);
                float x = h1s[g][hh + (s << 1)];
                a0 = fmaf(x, w.x, a0);
                a1 = fmaf(x, w.y, a1);
            }
            gpart[g][hh][o2+0] = a0; gpart[g][hh][o2+1] = a1;
        }
        __syncthreads();
        h2s[g][tt] = sigmoidf_(gpart[g][0][tt] + gpart[g][1][tt]);
        __syncthreads();

        // critic layer 3 (128->32): s=0..63 sequential, tt<32
        if (tt < 32) {
            const int o2 = (tt & 15) << 1;
            const int hh = tt >> 4;
            float a0 = hh ? 0.0f : bc3[o2+0];
            float a1 = hh ? 0.0f : bc3[o2+1];
            #pragma unroll
            for (int s = 0; s < 64; ++s) {
                f2 w = *(const f2*)(Wc3 + (size_t)(hh + (s << 1)) * 32 + o2);
                float x = h2s[g][hh + (s << 1)];
                a0 = fmaf(x, w.x, a0);
                a1 = fmaf(x, w.y, a1);
            }
            gpart[g][hh][o2+0] = a0; gpart[g][hh][o2+1] = a1;
        }
        __syncthreads();
        if (tt < 32) h3s[g][tt] = sigmoidf_(gpart[g][0][tt] + gpart[g][1][tt]);
        __syncthreads();

        if (tt == 0) {
            float l4 = bc4[0];
            for (int i = 0; i < 32; ++i) l4 = fmaf(h3s[g][i], Wc4[i], l4);
            cr_c[kk] = l4;             // no sigmoid on final critic layer
        }
    }
}

// Merged scatter: blocks [0, vecBlocks) emit BOTH am and sd float4 per
// thread from one obs read + one idx_t indirection (L1-hot, 4 KB);
// trailing blocks do the critic/idx scatter and vq_loss reduction.
__global__ __launch_bounds__(256) void scatter_kernel(
    const int* __restrict__ obs,
    const f4* __restrict__ am_c, const f4* __restrict__ sd_c,
    const float* __restrict__ cr_c, const int* __restrict__ idx_t,
    const float* __restrict__ e_t,
    f4* __restrict__ out_vec, float* __restrict__ out_critic,
    float* __restrict__ out_idx, float* __restrict__ out_loss,
    int B, float scale)
{
    __shared__ float red[256];
    const int vecBlocks = (B * 32) / 256;           // B*128/4 f4-slots per half
    if ((int)blockIdx.x < vecBlocks) {
        int gid = blockIdx.x * 256 + threadIdx.x;
        int b = gid >> 5;                           // 32 float4 per row
        int j = gid & 31;
        int k = idx_t[obs[b]];
        size_t row = (size_t)k * 32 + j;
        __builtin_nontemporal_store(am_c[row], &out_vec[gid]);
        __builtin_nontemporal_store(sd_c[row], &out_vec[(size_t)B * 32 + gid]);
        return;
    }
    int b = (blockIdx.x - vecBlocks) * 256 + threadIdx.x;
    float e = 0.0f;
    if (b < B) {
        int o = obs[b];
        int k = idx_t[o];
        __builtin_nontemporal_store(cr_c[k], &out_critic[b]);
        __builtin_nontemporal_store((float)k, &out_idx[b]);
        e = e_t[o];
    }
    red[threadIdx.x] = e;
    __syncthreads();
    for (int s = 128; s > 0; s >>= 1) {
        if (threadIdx.x < s) red[threadIdx.x] += red[threadIdx.x + s];
        __syncthreads();
    }
    if (threadIdx.x == 0) atomicAdd(out_loss, red[0] * scale);
}

extern "C" void kernel_launch(void* const* d_in, const int* in_sizes, int n_in,
                              void* d_out, int out_size, void* d_ws, size_t ws_size,
                              hipStream_t stream)
{
    const int*   obs   = (const int*)  d_in[0];
    const float* embed = (const float*)d_in[1];
    const float* W1    = (const float*)d_in[2];
    const float* b1    = (const float*)d_in[3];
    const float* W2    = (const float*)d_in[4];
    const float* b2    = (const float*)d_in[5];
    const float* W3    = (const float*)d_in[6];
    const float* b3    = (const float*)d_in[7];
    const float* Wp    = (const float*)d_in[8];
    const float* bp    = (const float*)d_in[9];
    const float* cb    = (const float*)d_in[10];
    const float* Wa    = (const float*)d_in[11];
    const float* ba    = (const float*)d_in[12];
    const float* Ws    = (const float*)d_in[13];
    const float* bs    = (const float*)d_in[14];
    const float* Wc1   = (const float*)d_in[15];
    const float* bc1   = (const float*)d_in[16];
    const float* Wc2   = (const float*)d_in[17];
    const float* bc2   = (const float*)d_in[18];
    const float* Wc3   = (const float*)d_in[19];
    const float* bc3   = (const float*)d_in[20];
    const float* Wc4   = (const float*)d_in[21];
    const float* bc4   = (const float*)d_in[22];

    const int B   = in_sizes[0];
    const int NC  = in_sizes[1] / 128;
    const int VQN = in_sizes[10] / 64;

    // workspace tables: per-code am/sd/cr + per-class idx/e (~530 KB)
    float* am_c = (float*)d_ws;
    float* sd_c = am_c + (size_t)VQN * 128;
    float* cr_c = sd_c + (size_t)VQN * 128;
    float* e_t  = cr_c + VQN;
    int*   idx_t = (int*)(e_t + NC);

    float* out = (float*)d_out;
    const size_t cr_off   = (size_t)B * 256;     // after am (B*128) + sd (B*128)
    const size_t loss_off = cr_off + (size_t)B;
    const size_t idx_off  = loss_off + 1;

    const int nTB = (NC + 7) / 8;                // trunk blocks (8 classes each)
    const int nHB = (VQN + 1) / 2;               // head blocks (2 codes each)

    compute_kernel<<<nTB + nHB, 256, 0, stream>>>(
        embed, W1, b1, W2, b2, W3, b3, Wp, bp, cb,
        Wa, ba, Ws, bs, Wc1, bc1, Wc2, bc2, Wc3, bc3, Wc4, bc4,
        am_c, sd_c, cr_c, idx_t, e_t, out + loss_off, VQN, NC, nTB);

    const int vecBlocks    = (B * 32) / 256;
    const int scalarBlocks = (B + 255) / 256;
    scatter_kernel<<<vecBlocks + scalarBlocks, 256, 0, stream>>>(
        obs, (const f4*)am_c, (const f4*)sd_c, cr_c, idx_t, e_t,
        (f4*)out, out + cr_off, out + idx_off, out + loss_off,
        B, 1.25f / ((float)B * 64.0f));
}

// Round 11
// 235.955 us; speedup vs baseline: 1.2488x; 1.2488x over previous
//
#include <hip/hip_runtime.h>
#include <math.h>

// Outputs are a pure function of obs's class (NC=1000); heads (am/sd/cr)
// are a pure function of the VQ CODE (VQN=512). Structure as R8:
//   compute kernel: blocks [0,nTB) trunk+VQ (2 classes, shared f4 loads);
//                   blocks [nTB,+nHB) heads per code (2 codes/block).
//   scatter: out[b] = tables[idx_t[obs[b]]].
//
// R14 = verbatim restore of the empirical optimum (R9 kernel, 234.4 us).
// Investigation closed: VMEM scheduling (R9/R10 null), occupancy cap
// (R11 spill), traffic amortization (R6/R12 regress), wave-per-class
// (R13: 100us, VALUBusy 7.3% -> latency-bound serial chain insensitive
// to structure). Budget: 171us harness fills (78-85% HBM peak) + 21us
// scatter (134MB mandatory writes at write roofline) + ~42us compute.

typedef float f4 __attribute__((ext_vector_type(4)));
typedef float f2 __attribute__((ext_vector_type(2)));

__device__ __forceinline__ float sigmoidf_(float x){ return 1.0f/(1.0f + expf(-x)); }

__global__ __launch_bounds__(256) void compute_kernel(
    const float* __restrict__ embed,
    const float* __restrict__ W1, const float* __restrict__ b1,
    const float* __restrict__ W2, const float* __restrict__ b2,
    const float* __restrict__ W3, const float* __restrict__ b3,
    const float* __restrict__ Wp, const float* __restrict__ bp,
    const float* __restrict__ cb,
    const float* __restrict__ Wa, const float* __restrict__ ba,
    const float* __restrict__ Ws, const float* __restrict__ bs,
    const float* __restrict__ Wc1, const float* __restrict__ bc1,
    const float* __restrict__ Wc2, const float* __restrict__ bc2,
    const float* __restrict__ Wc3, const float* __restrict__ bc3,
    const float* __restrict__ Wc4, const float* __restrict__ bc4,
    float* __restrict__ am_c, float* __restrict__ sd_c,
    float* __restrict__ cr_c, int* __restrict__ idx_t, float* __restrict__ e_t,
    float* __restrict__ loss_slot, int VQN, int NC, int nTB)
{
    const int bid = blockIdx.x;
    const int t   = threadIdx.x;     // 0..255
    if (bid == 0 && t == 0) *loss_slot = 0.0f;   // d_out is poisoned each call

    // trunk-branch LDS
    __shared__ double U[2][128], V[2][128];     // layer ping-pong (class A/B)
    __shared__ double part[2][8][128];          // fp64 chain partials
    __shared__ double zp2[2][64];
    __shared__ float  qv2[2][64];
    __shared__ double rda[2][4];
    __shared__ int    ria[2][4];
    __shared__ int    widx2[2];
    // head-branch LDS
    __shared__ float  qvh[2][64];
    __shared__ float  fpart[2][4][128];
    __shared__ float  gpart[2][2][128];
    __shared__ float  h1s[2][128], h2s[2][128], h3s[2][32];

    if (bid < nTB) {
        // ================= trunk + VQ for classes c0, c1 =================
        const int c0  = bid * 2;
        const int c1  = (c0 + 1 < NC) ? c0 + 1 : NC - 1;   // clamp (dup-safe)
        const int cls = t >> 7;          // this thread's class for combines
        const int r   = t & 127;
        const int q4  = (t & 31) << 2;   // output quad (shared-load phases)
        const int h   = t >> 5;          // K-chain 0..7 (i ≡ h mod 8)

        if (t < 128) U[0][t] = (double)embed[(size_t)c0 * 128 + t];
        else         U[1][r] = (double)embed[(size_t)c1 * 128 + r];
        __syncthreads();

        // trunk layer: batch-issue 16 f4 weight loads into regs, then FMA
        // with LDS inputs inline. Chain 0 carries the bias. Per-chain
        // accumulation order == R8.
#define TRUNK2(Wm, bv, IN, OUT)                                               \
        {                                                                     \
            f4 w[16];                                                         \
            _Pragma("unroll")                                                 \
            for (int s = 0; s < 16; ++s)                                      \
                w[s] = *(const f4*)(Wm + (size_t)(h + (s << 3)) * 128 + q4);  \
            f4 bb = *(const f4*)(bv + q4);                                    \
            double aA0 = (h == 0) ? (double)bb.x : 0.0;                       \
            double aA1 = (h == 0) ? (double)bb.y : 0.0;                       \
            double aA2 = (h == 0) ? (double)bb.z : 0.0;                       \
            double aA3 = (h == 0) ? (double)bb.w : 0.0;                       \
            double aB0 = aA0, aB1 = aA1, aB2 = aA2, aB3 = aA3;                \
            _Pragma("unroll")                                                 \
            for (int s = 0; s < 16; ++s) {                                    \
                int i = h + (s << 3);                                         \
                double w0 = (double)w[s].x, w1 = (double)w[s].y;              \
                double w2 = (double)w[s].z, w3 = (double)w[s].w;              \
                double xA = IN[0][i], xB = IN[1][i];                          \
                aA0 = fma(xA, w0, aA0);  aB0 = fma(xB, w0, aB0);              \
                aA1 = fma(xA, w1, aA1);  aB1 = fma(xB, w1, aB1);              \
                aA2 = fma(xA, w2, aA2);  aB2 = fma(xB, w2, aB2);              \
                aA3 = fma(xA, w3, aA3);  aB3 = fma(xB, w3, aB3);              \
            }                                                                 \
            part[0][h][q4+0] = aA0; part[0][h][q4+1] = aA1;                   \
            part[0][h][q4+2] = aA2; part[0][h][q4+3] = aA3;                   \
            part[1][h][q4+0] = aB0; part[1][h][q4+1] = aB1;                   \
            part[1][h][q4+2] = aB2; part[1][h][q4+3] = aB3;                   \
        }                                                                     \
        __syncthreads();                                                      \
        {                                                                     \
            double acc = ((part[cls][0][r] + part[cls][1][r])                 \
                        + (part[cls][2][r] + part[cls][3][r]))                \
                       + ((part[cls][4][r] + part[cls][5][r])                 \
                        + (part[cls][6][r] + part[cls][7][r]));               \
            OUT[cls][r] = acc > 0.0 ? acc : 0.0;                              \
        }                                                                     \
        __syncthreads();

        TRUNK2(W1, b1, U, V)
        TRUNK2(W2, b2, V, U)
        TRUNK2(W3, b3, U, V)
#undef TRUNK2

        // zp = z3 @ Wp + bp (64 outs/class): 8 chains x 16 quads, batched
        {
            const int q4p = (r & 15) << 2;
            const int hp  = r >> 4;          // 0..7
            f4 w[16];
            #pragma unroll
            for (int s = 0; s < 16; ++s)
                w[s] = *(const f4*)(Wp + (size_t)(hp + (s << 3)) * 64 + q4p);
            f4 bb = *(const f4*)(bp + q4p);
            double a0 = (hp == 0) ? (double)bb.x : 0.0;
            double a1 = (hp == 0) ? (double)bb.y : 0.0;
            double a2 = (hp == 0) ? (double)bb.z : 0.0;
            double a3 = (hp == 0) ? (double)bb.w : 0.0;
            #pragma unroll
            for (int s = 0; s < 16; ++s) {
                int i = hp + (s << 3);
                double x = V[cls][i];
                a0 = fma(x, (double)w[s].x, a0);
                a1 = fma(x, (double)w[s].y, a1);
                a2 = fma(x, (double)w[s].z, a2);
                a3 = fma(x, (double)w[s].w, a3);
            }
            part[cls][hp][q4p+0] = a0; part[cls][hp][q4p+1] = a1;
            part[cls][hp][q4p+2] = a2; part[cls][hp][q4p+3] = a3;
        }
        __syncthreads();
        if (r < 64) {
            zp2[cls][r] = ((part[cls][0][r] + part[cls][1][r])
                         + (part[cls][2][r] + part[cls][3][r]))
                        + ((part[cls][4][r] + part[cls][5][r])
                         + (part[cls][6][r] + part[cls][7][r]));
        }
        __syncthreads();

        // VQ argmin: thread t owns codes t, t+256; batch each code's 16
        // row-f4s into regs, then distance chains (R8's exact order).
        double bestA = 1e300, bestB = 1e300; int biA = 0, biB = 0;
        for (int k = t; k < VQN; k += 256) {
            const float* crow = cb + (size_t)k * 64;
            f4 v[16];
            #pragma unroll
            for (int j4 = 0; j4 < 16; ++j4)
                v[j4] = *(const f4*)(crow + (j4 << 2));
            double sA0 = 0.0, sA1 = 0.0, sB0 = 0.0, sB1 = 0.0;
            #pragma unroll
            for (int j4 = 0; j4 < 16; ++j4) {
                int j = j4 << 2;
                double w0 = (double)v[j4].x, w1 = (double)v[j4].y;
                double w2 = (double)v[j4].z, w3 = (double)v[j4].w;
                double dA0 = zp2[0][j+0] - w0, dA1 = zp2[0][j+1] - w1;
                double dA2 = zp2[0][j+2] - w2, dA3 = zp2[0][j+3] - w3;
                double dB0 = zp2[1][j+0] - w0, dB1 = zp2[1][j+1] - w1;
                double dB2 = zp2[1][j+2] - w2, dB3 = zp2[1][j+3] - w3;
                sA0 = fma(dA0, dA0, sA0);  sA1 = fma(dA1, dA1, sA1);
                sA0 = fma(dA2, dA2, sA0);  sA1 = fma(dA3, dA3, sA1);
                sB0 = fma(dB0, dB0, sB0);  sB1 = fma(dB1, dB1, sB1);
                sB0 = fma(dB2, dB2, sB0);  sB1 = fma(dB3, dB3, sB1);
            }
            double sA = sA0 + sA1, sB = sB0 + sB1;
            if (sA < bestA) { bestA = sA; biA = k; }   // first-min, ascending
            if (sB < bestB) { bestB = sB; biB = k; }
        }
        // (min d, min idx) lattice within wave, then across 4 waves via LDS
        for (int off = 32; off > 0; off >>= 1) {
            double od = __shfl_down(bestA, off);
            int    oi = __shfl_down(biA, off);
            if (od < bestA || (od == bestA && oi < biA)) { bestA = od; biA = oi; }
            od = __shfl_down(bestB, off);
            oi = __shfl_down(biB, off);
            if (od < bestB || (od == bestB && oi < biB)) { bestB = od; biB = oi; }
        }
        {
            int wv = t >> 6;
            if ((t & 63) == 0) {
                rda[0][wv] = bestA; ria[0][wv] = biA;
                rda[1][wv] = bestB; ria[1][wv] = biB;
            }
        }
        __syncthreads();
        if (t < 2) {
            double b0 = rda[t][0]; int i0 = ria[t][0];
            for (int wv = 1; wv < 4; ++wv) {
                if (rda[t][wv] < b0 || (rda[t][wv] == b0 && ria[t][wv] < i0)) {
                    b0 = rda[t][wv]; i0 = ria[t][wv];
                }
            }
            widx2[t] = i0;
        }
        __syncthreads();
        const int widxA = widx2[0], widxB = widx2[1];
        if (t < 64)       qv2[0][t]      = cb[(size_t)widxA * 64 + t];
        else if (t < 128) qv2[1][t - 64] = cb[(size_t)widxB * 64 + (t - 64)];
        __syncthreads();

        if (t == 0) {
            idx_t[c0] = widxA;
            double e0 = 0.0, e1 = 0.0;
            for (int j = 0; j < 64; j += 2) {
                double d0 = (double)qv2[0][j]   - zp2[0][j];
                double d1 = (double)qv2[0][j+1] - zp2[0][j+1];
                e0 = fma(d0, d0, e0); e1 = fma(d1, d1, e1);
            }
            e_t[c0] = (float)(e0 + e1);
        }
        if (t == 128 && c1 != c0) {
            idx_t[c1] = widxB;
            double e0 = 0.0, e1 = 0.0;
            for (int j = 0; j < 64; j += 2) {
                double d0 = (double)qv2[1][j]   - zp2[1][j];
                double d1 = (double)qv2[1][j+1] - zp2[1][j+1];
                e0 = fma(d0, d0, e0); e1 = fma(d1, d1, e1);
            }
            e_t[c1] = (float)(e0 + e1);
        }
    } else {
        // ============ heads per CODE (2 codes/block, batched loads) ============
        const int g  = t >> 7;                 // code slot 0/1
        const int tt = t & 127;
        int k = (bid - nTB) * 2 + g;
        const int kk = (k < VQN) ? k : VQN - 1;    // clamp (dup-safe)
        const int q4 = (tt & 31) << 2;

        if (tt < 64) qvh[g][tt] = cb[(size_t)kk * 64 + tt];
        __syncthreads();

        // H1: slots (tt>>5): 0=Wa-even, 1=Wa-odd, 2=Ws-even, 3=Ws-odd.
        // 32 f4 loads as two batched groups of 16; chain order == R8.
        {
            const int m  = tt >> 6;
            const int hh = (tt >> 5) & 1;
            const float* Wm = m ? Ws : Wa;
            const float* bm = m ? bs : ba;
            f4 bb = *(const f4*)(bm + q4);
            float a0 = hh ? 0.0f : bb.x;
            float a1 = hh ? 0.0f : bb.y;
            float a2 = hh ? 0.0f : bb.z;
            float a3 = hh ? 0.0f : bb.w;
            f4 w[16];
            #pragma unroll
            for (int s = 0; s < 16; ++s)
                w[s] = *(const f4*)(Wm + (size_t)(hh + (s << 1)) * 128 + q4);
            #pragma unroll
            for (int s = 0; s < 16; ++s) {
                float qj = qvh[g][hh + (s << 1)];
                a0 = fmaf(qj, w[s].x, a0);
                a1 = fmaf(qj, w[s].y, a1);
                a2 = fmaf(qj, w[s].z, a2);
                a3 = fmaf(qj, w[s].w, a3);
            }
            #pragma unroll
            for (int s = 0; s < 16; ++s)
                w[s] = *(const f4*)(Wm + (size_t)(hh + ((s + 16) << 1)) * 128 + q4);
            #pragma unroll
            for (int s = 0; s < 16; ++s) {
                float qj = qvh[g][hh + ((s + 16) << 1)];
                a0 = fmaf(qj, w[s].x, a0);
                a1 = fmaf(qj, w[s].y, a1);
                a2 = fmaf(qj, w[s].z, a2);
                a3 = fmaf(qj, w[s].w, a3);
            }
            fpart[g][tt >> 5][q4+0] = a0; fpart[g][tt >> 5][q4+1] = a1;
            fpart[g][tt >> 5][q4+2] = a2; fpart[g][tt >> 5][q4+3] = a3;
        }
        __syncthreads();

        // H2: tt<64 compute Wc1 chains (batched); tt>=64 combine+store am/sd
        if (tt < 64) {
            const int hh = tt >> 5;
            f4 bb = *(const f4*)(bc1 + q4);
            float a0 = hh ? 0.0f : bb.x;
            float a1 = hh ? 0.0f : bb.y;
            float a2 = hh ? 0.0f : bb.z;
            float a3 = hh ? 0.0f : bb.w;
            f4 w[16];
            #pragma unroll
            for (int s = 0; s < 16; ++s)
                w[s] = *(const f4*)(Wc1 + (size_t)(hh + (s << 1)) * 128 + q4);
            #pragma unroll
            for (int s = 0; s < 16; ++s) {
                float qj = qvh[g][hh + (s << 1)];
                a0 = fmaf(qj, w[s].x, a0);
                a1 = fmaf(qj, w[s].y, a1);
                a2 = fmaf(qj, w[s].z, a2);
                a3 = fmaf(qj, w[s].w, a3);
            }
            #pragma unroll
            for (int s = 0; s < 16; ++s)
                w[s] = *(const f4*)(Wc1 + (size_t)(hh + ((s + 16) << 1)) * 128 + q4);
            #pragma unroll
            for (int s = 0; s < 16; ++s) {
                float qj = qvh[g][hh + ((s + 16) << 1)];
                a0 = fmaf(qj, w[s].x, a0);
                a1 = fmaf(qj, w[s].y, a1);
                a2 = fmaf(qj, w[s].z, a2);
                a3 = fmaf(qj, w[s].w, a3);
            }
            gpart[g][hh][q4+0] = a0; gpart[g][hh][q4+1] = a1;
            gpart[g][hh][q4+2] = a2; gpart[g][hh][q4+3] = a3;
        } else {
            int o = (tt - 64) << 1;
            am_c[(size_t)kk * 128 + o]     = sigmoidf_(fpart[g][0][o]   + fpart[g][1][o]);
            am_c[(size_t)kk * 128 + o + 1] = sigmoidf_(fpart[g][0][o+1] + fpart[g][1][o+1]);
            sd_c[(size_t)kk * 128 + o]     = sigmoidf_(fpart[g][2][o]   + fpart[g][3][o])   * 1.0f + 1e-8f;
            sd_c[(size_t)kk * 128 + o + 1] = sigmoidf_(fpart[g][2][o+1] + fpart[g][3][o+1]) * 1.0f + 1e-8f;
        }
        __syncthreads();
        h1s[g][tt] = sigmoidf_(gpart[g][0][tt] + gpart[g][1][tt]);
        __syncthreads();

        // critic layer 2 (128->128): 64 iters as 4 batched groups of 16 f2
        {
            const int o2 = (tt & 63) << 1;
            const int hh = tt >> 6;
            f2 bb = *(const f2*)(bc2 + o2);
            float a0 = hh ? 0.0f : bb.x;
            float a1 = hh ? 0.0f : bb.y;
            #pragma unroll
            for (int gq = 0; gq < 4; ++gq) {
                f2 w[16];
                #pragma unroll
                for (int s = 0; s < 16; ++s) {
                    int i = hh + (((gq << 4) + s) << 1);
                    w[s] = *(const f2*)(Wc2 + (size_t)i * 128 + o2);
                }
                #pragma unroll
                for (int s = 0; s < 16; ++s) {
                    int i = hh + (((gq << 4) + s) << 1);
                    float x = h1s[g][i];
                    a0 = fmaf(x, w[s].x, a0);
                    a1 = fmaf(x, w[s].y, a1);
                }
            }
            gpart[g][hh][o2+0] = a0; gpart[g][hh][o2+1] = a1;
        }
        __syncthreads();
        h2s[g][tt] = sigmoidf_(gpart[g][0][tt] + gpart[g][1][tt]);
        __syncthreads();

        // critic layer 3 (128->32): 4 batched groups of 16 f2, tt<32
        if (tt < 32) {
            const int o2 = (tt & 15) << 1;
            const int hh = tt >> 4;
            f2 bb = *(const f2*)(bc3 + o2);
            float a0 = hh ? 0.0f : bb.x;
            float a1 = hh ? 0.0f : bb.y;
            #pragma unroll
            for (int gq = 0; gq < 4; ++gq) {
                f2 w[16];
                #pragma unroll
                for (int s = 0; s < 16; ++s) {
                    int i = hh + (((gq << 4) + s) << 1);
                    w[s] = *(const f2*)(Wc3 + (size_t)i * 32 + o2);
                }
                #pragma unroll
                for (int s = 0; s < 16; ++s) {
                    int i = hh + (((gq << 4) + s) << 1);
                    float x = h2s[g][i];
                    a0 = fmaf(x, w[s].x, a0);
                    a1 = fmaf(x, w[s].y, a1);
                }
            }
            gpart[g][hh][o2+0] = a0; gpart[g][hh][o2+1] = a1;
        }
        __syncthreads();
        if (tt < 32) h3s[g][tt] = sigmoidf_(gpart[g][0][tt] + gpart[g][1][tt]);
        __syncthreads();

        if (tt == 0) {
            float l4 = bc4[0];
            for (int i = 0; i < 32; ++i) l4 = fmaf(h3s[g][i], Wc4[i], l4);
            cr_c[kk] = l4;             // no sigmoid on final critic layer
        }
    }
}

// Merged scatter: blocks [0, vecBlocks) emit BOTH am and sd float4 per
// thread from one obs read + one idx_t indirection (L1-hot, 4 KB);
// trailing blocks do the critic/idx scatter and vq_loss reduction.
__global__ __launch_bounds__(256) void scatter_kernel(
    const int* __restrict__ obs,
    const f4* __restrict__ am_c, const f4* __restrict__ sd_c,
    const float* __restrict__ cr_c, const int* __restrict__ idx_t,
    const float* __restrict__ e_t,
    f4* __restrict__ out_vec, float* __restrict__ out_critic,
    float* __restrict__ out_idx, float* __restrict__ out_loss,
    int B, float scale)
{
    __shared__ float red[256];
    const int vecBlocks = (B * 32) / 256;           // B*128/4 f4-slots per half
    if ((int)blockIdx.x < vecBlocks) {
        int gid = blockIdx.x * 256 + threadIdx.x;
        int b = gid >> 5;                           // 32 float4 per row
        int j = gid & 31;
        int k = idx_t[obs[b]];
        size_t row = (size_t)k * 32 + j;
        __builtin_nontemporal_store(am_c[row], &out_vec[gid]);
        __builtin_nontemporal_store(sd_c[row], &out_vec[(size_t)B * 32 + gid]);
        return;
    }
    int b = (blockIdx.x - vecBlocks) * 256 + threadIdx.x;
    float e = 0.0f;
    if (b < B) {
        int o = obs[b];
        int k = idx_t[o];
        __builtin_nontemporal_store(cr_c[k], &out_critic[b]);
        __builtin_nontemporal_store((float)k, &out_idx[b]);
        e = e_t[o];
    }
    red[threadIdx.x] = e;
    __syncthreads();
    for (int s = 128; s > 0; s >>= 1) {
        if (threadIdx.x < s) red[threadIdx.x] += red[threadIdx.x + s];
        __syncthreads();
    }
    if (threadIdx.x == 0) atomicAdd(out_loss, red[0] * scale);
}

extern "C" void kernel_launch(void* const* d_in, const int* in_sizes, int n_in,
                              void* d_out, int out_size, void* d_ws, size_t ws_size,
                              hipStream_t stream)
{
    const int*   obs   = (const int*)  d_in[0];
    const float* embed = (const float*)d_in[1];
    const float* W1    = (const float*)d_in[2];
    const float* b1    = (const float*)d_in[3];
    const float* W2    = (const float*)d_in[4];
    const float* b2    = (const float*)d_in[5];
    const float* W3    = (const float*)d_in[6];
    const float* b3    = (const float*)d_in[7];
    const float* Wp    = (const float*)d_in[8];
    const float* bp    = (const float*)d_in[9];
    const float* cb    = (const float*)d_in[10];
    const float* Wa    = (const float*)d_in[11];
    const float* ba    = (const float*)d_in[12];
    const float* Ws    = (const float*)d_in[13];
    const float* bs    = (const float*)d_in[14];
    const float* Wc1   = (const float*)d_in[15];
    const float* bc1   = (const float*)d_in[16];
    const float* Wc2   = (const float*)d_in[17];
    const float* bc2   = (const float*)d_in[18];
    const float* Wc3   = (const float*)d_in[19];
    const float* bc3   = (const float*)d_in[20];
    const float* Wc4   = (const float*)d_in[21];
    const float* bc4   = (const float*)d_in[22];

    const int B   = in_sizes[0];
    const int NC  = in_sizes[1] / 128;
    const int VQN = in_sizes[10] / 64;

    // workspace tables: per-code am/sd/cr + per-class idx/e (~530 KB)
    float* am_c = (float*)d_ws;
    float* sd_c = am_c + (size_t)VQN * 128;
    float* cr_c = sd_c + (size_t)VQN * 128;
    float* e_t  = cr_c + VQN;
    int*   idx_t = (int*)(e_t + NC);

    float* out = (float*)d_out;
    const size_t cr_off   = (size_t)B * 256;     // after am (B*128) + sd (B*128)
    const size_t loss_off = cr_off + (size_t)B;
    const size_t idx_off  = loss_off + 1;

    const int nTB = (NC + 1) / 2;                // trunk blocks (2 classes each)
    const int nHB = (VQN + 1) / 2;               // head blocks (2 codes each)

    compute_kernel<<<nTB + nHB, 256, 0, stream>>>(
        embed, W1, b1, W2, b2, W3, b3, Wp, bp, cb,
        Wa, ba, Ws, bs, Wc1, bc1, Wc2, bc2, Wc3, bc3, Wc4, bc4,
        am_c, sd_c, cr_c, idx_t, e_t, out + loss_off, VQN, NC, nTB);

    const int vecBlocks    = (B * 32) / 256;
    const int scalarBlocks = (B + 255) / 256;
    scatter_kernel<<<vecBlocks + scalarBlocks, 256, 0, stream>>>(
        obs, (const f4*)am_c, (const f4*)sd_c, cr_c, idx_t, e_t,
        (f4*)out, out + cr_off, out + idx_off, out + loss_off,
        B, 1.25f / ((float)B * 64.0f));
}